// Round 1
// baseline (351.374 us; speedup 1.0000x reference)
//
#include <hip/hip_runtime.h>

// ---------------------------------------------------------------------------
// STCAOutputLayer: h = x@w  (GEMM, bf16 MFMA);  E == 0 identically (spk never
// set in reference), so out[b,t,d] = (M_t - S_t)*inv_norm[d] - bias[d] with
// M_t = dm*(M_{t-1}+h_t), S_t = ds*(S_{t-1}+h_t).  Plus loss = 0.5*mean(out^2).
//
// Shapes: B=32 T=500 IN=2048 OUT=1024; M = B*T = 16000 = 125*128 exactly,
// N = 1024 = 8*128, K = 2048 = 64*32 -> no edge cases anywhere.
// ---------------------------------------------------------------------------

typedef __bf16 bf16x8 __attribute__((ext_vector_type(8)));
typedef __bf16 bf16x4 __attribute__((ext_vector_type(4)));
typedef float  f32x4  __attribute__((ext_vector_type(4)));

#define BDIM 32
#define TDIM 500
#define INDIM 2048
#define OUTDIM 1024
#define MROWS 16000            // B*T
#define NCHUNK 25              // scan chunks
#define CHLEN 20               // 25*20 = 500
#define OUT_ELEMS 16384000     // B*T*OUT

// ---- global -> LDS async copy, 16B per lane, LDS dest = base + lane*16 ----
__device__ __forceinline__ void gld_lds16(const void* g, void* l) {
    __builtin_amdgcn_global_load_lds(
        (const __attribute__((address_space(1))) unsigned int*)g,
        (__attribute__((address_space(3))) unsigned int*)l, 16, 0, 0);
}

// ---------------------------------------------------------------------------
// fp32 -> bf16 convert of x (pure elementwise). 8 elems / thread.
__global__ void convert_x(const float* __restrict__ x, __bf16* __restrict__ xb) {
    size_t i = ((size_t)blockIdx.x * 256 + threadIdx.x) * 8;
    float4 a = *(const float4*)(x + i);
    float4 b = *(const float4*)(x + i + 4);
    bf16x8 o;
    o[0] = (__bf16)a.x; o[1] = (__bf16)a.y; o[2] = (__bf16)a.z; o[3] = (__bf16)a.w;
    o[4] = (__bf16)b.x; o[5] = (__bf16)b.y; o[6] = (__bf16)b.z; o[7] = (__bf16)b.w;
    *(bf16x8*)(xb + i) = o;
}

// ---------------------------------------------------------------------------
// w [K=2048][N=1024] fp32  ->  wbt [N][K] bf16 (transposed, k-contiguous).
__global__ void transpose_w(const float* __restrict__ w, __bf16* __restrict__ wbt) {
    __shared__ float tile[32][33];
    const int tx = threadIdx.x;        // 0..31
    const int ty = threadIdx.y;        // 0..7
    const int d0 = blockIdx.x * 32;    // N tile
    const int c0 = blockIdx.y * 32;    // K tile
#pragma unroll
    for (int i = 0; i < 4; ++i) {
        int c = c0 + ty + i * 8;
        tile[ty + i * 8][tx] = w[(size_t)c * OUTDIM + d0 + tx];
    }
    __syncthreads();
#pragma unroll
    for (int i = 0; i < 4; ++i) {
        int d = d0 + ty + i * 8;
        wbt[(size_t)d * INDIM + c0 + tx] = (__bf16)tile[tx][ty + i * 8];
    }
}

// ---------------------------------------------------------------------------
// norm[d] = sum_c w[c][d]^2  (fp32, from original w).  128 blocks x 16 rows.
__global__ void norm_w(const float* __restrict__ w, float* __restrict__ normAcc) {
    const int tid = threadIdx.x;
    const int c0 = blockIdx.x * 16;
    float acc0 = 0.f, acc1 = 0.f, acc2 = 0.f, acc3 = 0.f;
    for (int c = c0; c < c0 + 16; ++c) {
        const float* row = w + (size_t)c * OUTDIM;
        float v0 = row[tid];       acc0 += v0 * v0;
        float v1 = row[tid + 256]; acc1 += v1 * v1;
        float v2 = row[tid + 512]; acc2 += v2 * v2;
        float v3 = row[tid + 768]; acc3 += v3 * v3;
    }
    atomicAdd(&normAcc[tid], acc0);
    atomicAdd(&normAcc[tid + 256], acc1);
    atomicAdd(&normAcc[tid + 512], acc2);
    atomicAdd(&normAcc[tid + 768], acc3);
}

// ---------------------------------------------------------------------------
// GEMM: H[m][n] = sum_k A[m][k]*Bt[n][k], bf16 in, bf16 out (fp32 acc).
// 128x128 tile, 4 waves in 2x2, each wave 64x64 via 4x4 MFMA 16x16x32 tiles.
// global_load_lds(16B) staging; XOR swizzle slot=(seg+f(row))&3,
// f(row)=((row&3)+((row>>2)&3))&3 -> ds_read_b128 frag reads are 2-way (free).
__global__ __launch_bounds__(256, 2) void gemm_bf16(
    const __bf16* __restrict__ A,   // [16000][2048]  (xb, lives in d_out)
    const __bf16* __restrict__ Bt,  // [1024][2048]
    __bf16* __restrict__ H)         // [16000][1024]
{
    constexpr int K = INDIM;
    __shared__ __align__(16) __bf16 As[128 * 32];
    __shared__ __align__(16) __bf16 Bs[128 * 32];

    const int tid  = threadIdx.x;
    const int wave = tid >> 6;
    const int lane = tid & 63;
    const int bm = blockIdx.y * 128;
    const int bn = blockIdx.x * 128;
    const int wm = (wave & 1) * 64;
    const int wn = (wave >> 1) * 64;

    // staging lane mapping: 16 rows/wave/round, 4 slots of 16B per row
    const int arow  = lane >> 2;
    const int aslot = lane & 3;
    // fragment lane mapping
    const int quad = lane >> 4;
    const int mrow = lane & 15;
    const int fr   = ((mrow & 3) + ((mrow >> 2) & 3)) & 3;
    const int slot = ((quad + fr) & 3) * 8;   // element offset of 16B slot

    f32x4 acc[4][4] = {};

    for (int k0 = 0; k0 < K; k0 += 32) {
        __syncthreads();   // prior iteration's LDS reads are complete
#pragma unroll
        for (int r = 0; r < 2; ++r) {
            const int rbase = r * 64 + wave * 16;     // wave-uniform
            const int row   = rbase + arow;           // per-lane row
            const int f = ((row & 3) + ((row >> 2) & 3)) & 3;
            const int q = (aslot - f) & 3;            // global 16B segment
            gld_lds16(A  + (size_t)(bm + row) * K + (k0 + q * 8), &As[rbase * 32]);
            gld_lds16(Bt + (size_t)(bn + row) * K + (k0 + q * 8), &Bs[rbase * 32]);
        }
        __syncthreads();   // vmcnt(0) drain: staged data visible

        bf16x8 af[4], bfr[4];
#pragma unroll
        for (int i = 0; i < 4; ++i) {
            af[i]  = *(const bf16x8*)&As[(wm + i * 16 + mrow) * 32 + slot];
            bfr[i] = *(const bf16x8*)&Bs[(wn + i * 16 + mrow) * 32 + slot];
        }
#pragma unroll
        for (int i = 0; i < 4; ++i)
#pragma unroll
            for (int j = 0; j < 4; ++j)
                acc[i][j] = __builtin_amdgcn_mfma_f32_16x16x32_bf16(
                    af[i], bfr[j], acc[i][j], 0, 0, 0);
    }

    // epilogue: D[row=(lane>>4)*4+reg][col=lane&15] (m89-verified layout)
#pragma unroll
    for (int i = 0; i < 4; ++i)
#pragma unroll
        for (int j = 0; j < 4; ++j)
#pragma unroll
            for (int r = 0; r < 4; ++r) {
                const int R = bm + wm + i * 16 + quad * 4 + r;
                const int C = bn + wn + j * 16 + mrow;
                H[(size_t)R * OUTDIM + C] = (__bf16)acc[i][j][r];
            }
}

// ---------------------------------------------------------------------------
// scan pass 1: per (chunk c, batch b): local M/S with zero carry-in; store
// chunk-end values.  256 threads cover all 1024 d (float4 each).
__global__ void scan1(const __bf16* __restrict__ H,
                      f32x4* __restrict__ cM, f32x4* __restrict__ cS,
                      const float* __restrict__ dmp, const float* __restrict__ dsp) {
    const float dm = *dmp, ds = *dsp;
    const int c = blockIdx.x, b = blockIdx.y, tid = threadIdx.x;
    f32x4 M = {}, S = {};
    const __bf16* p = H + ((size_t)b * TDIM + c * CHLEN) * OUTDIM + tid * 4;
#pragma unroll 4
    for (int t = 0; t < CHLEN; ++t) {
        bf16x4 hv = *(const bf16x4*)(p + (size_t)t * OUTDIM);
        f32x4 h; h[0] = hv[0]; h[1] = hv[1]; h[2] = hv[2]; h[3] = hv[3];
        M = dm * (M + h);
        S = ds * (S + h);
    }
    const size_t idx = ((size_t)c * BDIM + b) * 256 + tid;
    cM[idx] = M;
    cS[idx] = S;
}

// ---------------------------------------------------------------------------
// scan pass 2: turn chunk-end values into per-chunk carry-INs (in place).
__global__ void scan2(f32x4* __restrict__ cM, f32x4* __restrict__ cS,
                      const float* __restrict__ dmp, const float* __restrict__ dsp) {
    const float dm = *dmp, ds = *dsp;
    float km = 1.f, ks = 1.f;
#pragma unroll
    for (int i = 0; i < CHLEN; ++i) { km *= dm; ks *= ds; }
    const int b = blockIdx.x, tid = threadIdx.x;
    f32x4 tM = {}, tS = {};
    for (int c = 0; c < NCHUNK; ++c) {
        const size_t idx = ((size_t)c * BDIM + b) * 256 + tid;
        f32x4 oM = cM[idx], oS = cS[idx];
        cM[idx] = tM; cS[idx] = tS;
        tM = km * tM + oM;
        tS = ks * tS + oS;
    }
}

// ---------------------------------------------------------------------------
// scan pass 3: recompute with carry-in, write out, accumulate loss.
__global__ void scan3(const __bf16* __restrict__ H,
                      const f32x4* __restrict__ cM, const f32x4* __restrict__ cS,
                      const float* __restrict__ normAcc, const float* __restrict__ bias,
                      const float* __restrict__ dmp, const float* __restrict__ dsp,
                      float* __restrict__ out, float* __restrict__ lossAcc) {
    const float dm = *dmp, ds = *dsp;
    const int c = blockIdx.x, b = blockIdx.y, tid = threadIdx.x;
    const size_t cidx = ((size_t)c * BDIM + b) * 256 + tid;
    f32x4 M = cM[cidx];
    f32x4 S = cS[cidx];
    f32x4 nv = *(const f32x4*)(normAcc + tid * 4);
    f32x4 inv;
    inv[0] = 1.f / (nv[0] + 1e-8f); inv[1] = 1.f / (nv[1] + 1e-8f);
    inv[2] = 1.f / (nv[2] + 1e-8f); inv[3] = 1.f / (nv[3] + 1e-8f);
    f32x4 bv = *(const f32x4*)(bias + tid * 4);

    const size_t rowbase = ((size_t)b * TDIM + c * CHLEN) * OUTDIM + tid * 4;
    const __bf16* p = H + rowbase;
    float* o = out + rowbase;
    float loss = 0.f;
#pragma unroll 4
    for (int t = 0; t < CHLEN; ++t) {
        bf16x4 hv = *(const bf16x4*)(p + (size_t)t * OUTDIM);
        f32x4 h; h[0] = hv[0]; h[1] = hv[1]; h[2] = hv[2]; h[3] = hv[3];
        M = dm * (M + h);
        S = ds * (S + h);
        f32x4 r = (M - S) * inv - bv;
        *(f32x4*)(o + (size_t)t * OUTDIM) = r;
        loss += r[0] * r[0] + r[1] * r[1] + r[2] * r[2] + r[3] * r[3];
    }
    __shared__ float red[256];
    red[tid] = loss;
    __syncthreads();
    for (int s = 128; s > 0; s >>= 1) {
        if (tid < s) red[tid] += red[tid + s];
        __syncthreads();
    }
    if (tid == 0) atomicAdd(lossAcc, red[0]);
}

// ---------------------------------------------------------------------------
__global__ void finalize(const float* __restrict__ lossAcc, float* __restrict__ out) {
    if (threadIdx.x == 0) out[OUT_ELEMS] = 0.5f * lossAcc[0] / (float)OUT_ELEMS;
}

// ---------------------------------------------------------------------------
// Workspace layout (bytes):
//   H    (bf16 16000x1024) : 0          .. 32,768,000
//   WBT  (bf16 1024x2048)  : 32,768,000 .. 36,962,304
//   NORM (f32 1024)        : 36,962,304 .. +4096
//   LOSS (f32 1)           : 36,966,400 .. +256
//   CM   (f32 25*32*1024)  : 36,966,656 .. +3,276,800
//   CS                     : 40,243,456 .. +3,276,800   (end 43,520,256)
// xb (bf16 x) lives in d_out (exactly 65,536,000 B) until scan3 overwrites it.
#define OFF_H    ((size_t)0)
#define OFF_WBT  ((size_t)32768000)
#define OFF_NORM ((size_t)36962304)
#define OFF_LOSS ((size_t)36966400)
#define OFF_CM   ((size_t)36966656)
#define OFF_CS   ((size_t)40243456)

extern "C" void kernel_launch(void* const* d_in, const int* in_sizes, int n_in,
                              void* d_out, int out_size, void* d_ws, size_t ws_size,
                              hipStream_t stream) {
    const float* x  = (const float*)d_in[0];
    const float* w  = (const float*)d_in[1];
    const float* bb = (const float*)d_in[2];
    const float* dm = (const float*)d_in[3];
    const float* ds = (const float*)d_in[4];

    char* ws = (char*)d_ws;
    __bf16* H    = (__bf16*)(ws + OFF_H);
    __bf16* WBT  = (__bf16*)(ws + OFF_WBT);
    float*  NORM = (float*)(ws + OFF_NORM);
    float*  LOSS = (float*)(ws + OFF_LOSS);
    f32x4*  CM   = (f32x4*)(ws + OFF_CM);
    f32x4*  CS   = (f32x4*)(ws + OFF_CS);
    __bf16* XB   = (__bf16*)d_out;          // scratch: bf16 x (exact fit)
    float*  out  = (float*)d_out;

    hipMemsetAsync(ws + OFF_NORM, 0, 4096 + 256, stream);

    convert_x<<<16000, 256, 0, stream>>>(x, XB);
    transpose_w<<<dim3(32, 64), dim3(32, 8), 0, stream>>>(w, WBT);
    norm_w<<<128, 256, 0, stream>>>(w, NORM);
    gemm_bf16<<<dim3(8, 125), 256, 0, stream>>>(XB, WBT, H);
    scan1<<<dim3(NCHUNK, BDIM), 256, 0, stream>>>(H, CM, CS, dm, ds);
    scan2<<<BDIM, 256, 0, stream>>>(CM, CS, dm, ds);
    scan3<<<dim3(NCHUNK, BDIM), 256, 0, stream>>>(H, CM, CS, NORM, bb, dm, ds, out, LOSS);
    finalize<<<1, 64, 0, stream>>>(LOSS, out);
}

// Round 2
// 334.976 us; speedup vs baseline: 1.0490x; 1.0490x over previous
//
#include <hip/hip_runtime.h>

// ---------------------------------------------------------------------------
// STCAOutputLayer: h = x@w (bf16 MFMA GEMM); E==0 identically (spk never set),
// out[b,t,d] = (M_t - S_t)*inv_norm[d] - bias[d],
// M_t = dm*(M_{t-1}+h_t), S_t = ds*(S_{t-1}+h_t); loss = 0.5*mean(out^2).
// Shapes: B=32 T=500 IN=2048 OUT=1024; M=B*T=16000=125*128, N=1024, K=2048.
//
// R2: GEMM was LDS-BW-bound (MfmaUtil 26%). New shape: block 128x256, BK=64,
// wave tile 128x64 (8x4 frags of 16x16x32) -> 42.7 FLOP/LDS-byte (was 32),
// staging writes amortized 2x. XOR-8 swizzle keeps ds_read_b128 conflict-min.
// ---------------------------------------------------------------------------

typedef __bf16 bf16x8 __attribute__((ext_vector_type(8)));
typedef __bf16 bf16x4 __attribute__((ext_vector_type(4)));
typedef float  f32x4  __attribute__((ext_vector_type(4)));

#define BDIM 32
#define TDIM 500
#define INDIM 2048
#define OUTDIM 1024
#define MROWS 16000            // B*T
#define NCHUNK 25              // scan chunks
#define CHLEN 20               // 25*20 = 500
#define OUT_ELEMS 16384000     // B*T*OUT

// ---- global -> LDS async copy, 16B per lane, LDS dest = base + lane*16 ----
__device__ __forceinline__ void gld_lds16(const void* g, void* l) {
    __builtin_amdgcn_global_load_lds(
        (const __attribute__((address_space(1))) unsigned int*)g,
        (__attribute__((address_space(3))) unsigned int*)l, 16, 0, 0);
}

// ---------------------------------------------------------------------------
// fp32 -> bf16 convert of x (pure elementwise). 8 elems / thread.
__global__ void convert_x(const float* __restrict__ x, __bf16* __restrict__ xb) {
    size_t i = ((size_t)blockIdx.x * 256 + threadIdx.x) * 8;
    float4 a = *(const float4*)(x + i);
    float4 b = *(const float4*)(x + i + 4);
    bf16x8 o;
    o[0] = (__bf16)a.x; o[1] = (__bf16)a.y; o[2] = (__bf16)a.z; o[3] = (__bf16)a.w;
    o[4] = (__bf16)b.x; o[5] = (__bf16)b.y; o[6] = (__bf16)b.z; o[7] = (__bf16)b.w;
    *(bf16x8*)(xb + i) = o;
}

// ---------------------------------------------------------------------------
// w [K=2048][N=1024] fp32 -> wbt [N][K] bf16, with fused norm[d]=sum_c w^2
// (fp32 partials from the staged tile, one atomicAdd per d per block).
__global__ void transpose_w(const float* __restrict__ w, __bf16* __restrict__ wbt,
                            float* __restrict__ normAcc) {
    __shared__ float tile[32][33];
    __shared__ float red[8][33];
    const int tx = threadIdx.x;        // 0..31
    const int ty = threadIdx.y;        // 0..7
    const int d0 = blockIdx.x * 32;    // N tile
    const int c0 = blockIdx.y * 32;    // K tile
    float s = 0.f;
#pragma unroll
    for (int i = 0; i < 4; ++i) {
        int c = c0 + ty + i * 8;
        float v = w[(size_t)c * OUTDIM + d0 + tx];
        tile[ty + i * 8][tx] = v;
        s += v * v;
    }
    red[ty][tx] = s;
    __syncthreads();
#pragma unroll
    for (int i = 0; i < 4; ++i) {
        int d = d0 + ty + i * 8;
        wbt[(size_t)d * INDIM + c0 + tx] = (__bf16)tile[tx][ty + i * 8];
    }
    if (ty == 0) {
        float t = red[0][tx] + red[1][tx] + red[2][tx] + red[3][tx]
                + red[4][tx] + red[5][tx] + red[6][tx] + red[7][tx];
        atomicAdd(&normAcc[d0 + tx], t);
    }
}

// ---------------------------------------------------------------------------
// GEMM: H[m][n] = sum_k A[m][k]*Bt[n][k], bf16 in/out (fp32 acc).
// Block tile 128(m) x 256(n), BK=64. 4 waves, each wave = 128m x 64n
// = 8x4 frags of mfma_f32_16x16x32_bf16 -> 42.7 FLOP per LDS-read byte.
// LDS rows are 64 bf16 = 8 segments of 16B; segment swizzle s' = s ^ (row&7):
// staging writes stay linear-in-lane (global_load_lds requirement) and
// ds_read_b128 frag reads hit all 8 bank-groups with 8 lanes each (minimum).
__global__ __launch_bounds__(256, 2) void gemm_bf16(
    const __bf16* __restrict__ A,   // [16000][2048]  (xb, lives in d_out)
    const __bf16* __restrict__ Bt,  // [1024][2048]
    __bf16* __restrict__ H)         // [16000][1024]
{
    constexpr int K = INDIM;
    __shared__ __align__(16) __bf16 As[128 * 64];   // 16 KB
    __shared__ __align__(16) __bf16 Bs[256 * 64];   // 32 KB

    const int tid  = threadIdx.x;
    const int wave = tid >> 6;
    const int lane = tid & 63;
    const int bm = blockIdx.y * 128;
    const int bn = blockIdx.x * 256;
    const int wn = wave * 64;

    // staging lane mapping: 8 rows x 8 segs of 16B per wave-instruction
    const int srow8 = lane >> 3;       // row within 8-row group
    const int sseg  = lane & 7;        // LDS segment this lane fills
    // fragment lane mapping (16x16x32: A[m=lane&15][k=quad*8+j])
    const int quad = lane >> 4;
    const int mrow = lane & 15;

    f32x4 acc[8][4] = {};

    for (int k0 = 0; k0 < K; k0 += 64) {
        __syncthreads();   // prior iteration's LDS reads complete
        // ---- stage A: 128 rows of 64 bf16 (128B), 4 instrs/wave ----
#pragma unroll
        for (int g = 0; g < 4; ++g) {
            const int rbase = wave * 32 + g * 8;           // wave-uniform
            const int row   = rbase + srow8;
            const int q     = sseg ^ (row & 7);            // global segment
            gld_lds16(A + (size_t)(bm + row) * K + k0 + q * 8, &As[rbase * 64]);
        }
        // ---- stage B: 256 rows, 8 instrs/wave ----
#pragma unroll
        for (int g = 0; g < 8; ++g) {
            const int rbase = wave * 64 + g * 8;           // wave-uniform
            const int row   = rbase + srow8;
            const int q     = sseg ^ (row & 7);
            gld_lds16(Bt + (size_t)(bn + row) * K + k0 + q * 8, &Bs[rbase * 64]);
        }
        __syncthreads();   // staged data visible

#pragma unroll
        for (int ks = 0; ks < 2; ++ks) {                   // two k=32 steps
            bf16x8 af[8], bfr[4];
#pragma unroll
            for (int i = 0; i < 8; ++i) {
                const int r = i * 16 + mrow;
                af[i] = *(const bf16x8*)&As[r * 64 + (((ks * 4 + quad) ^ (r & 7)) * 8)];
            }
#pragma unroll
            for (int j = 0; j < 4; ++j) {
                const int r = wn + j * 16 + mrow;
                bfr[j] = *(const bf16x8*)&Bs[r * 64 + (((ks * 4 + quad) ^ (r & 7)) * 8)];
            }
#pragma unroll
            for (int i = 0; i < 8; ++i)
#pragma unroll
                for (int j = 0; j < 4; ++j)
                    acc[i][j] = __builtin_amdgcn_mfma_f32_16x16x32_bf16(
                        af[i], bfr[j], acc[i][j], 0, 0, 0);
        }
    }

    // epilogue: D[row=quad*4+reg][col=mrow] (m89-verified layout)
#pragma unroll
    for (int i = 0; i < 8; ++i)
#pragma unroll
        for (int j = 0; j < 4; ++j)
#pragma unroll
            for (int r = 0; r < 4; ++r) {
                const int R = bm + i * 16 + quad * 4 + r;
                const int C = bn + wn + j * 16 + mrow;
                H[(size_t)R * OUTDIM + C] = (__bf16)acc[i][j][r];
            }
}

// ---------------------------------------------------------------------------
// scan pass 1: per (chunk c, batch b): local M/S with zero carry-in; store
// chunk-end values.  256 threads cover all 1024 d (float4 each).
__global__ void scan1(const __bf16* __restrict__ H,
                      f32x4* __restrict__ cM, f32x4* __restrict__ cS,
                      const float* __restrict__ dmp, const float* __restrict__ dsp) {
    const float dm = *dmp, ds = *dsp;
    const int c = blockIdx.x, b = blockIdx.y, tid = threadIdx.x;
    f32x4 M = {}, S = {};
    const __bf16* p = H + ((size_t)b * TDIM + c * CHLEN) * OUTDIM + tid * 4;
#pragma unroll 4
    for (int t = 0; t < CHLEN; ++t) {
        bf16x4 hv = *(const bf16x4*)(p + (size_t)t * OUTDIM);
        f32x4 h; h[0] = hv[0]; h[1] = hv[1]; h[2] = hv[2]; h[3] = hv[3];
        M = dm * (M + h);
        S = ds * (S + h);
    }
    const size_t idx = ((size_t)c * BDIM + b) * 256 + tid;
    cM[idx] = M;
    cS[idx] = S;
}

// ---------------------------------------------------------------------------
// scan pass 2: chunk-end values -> per-chunk carry-INs (in place).
// One scalar thread per (b,d): 32768 threads = 128 blocks.
__global__ void scan2(float* __restrict__ cM, float* __restrict__ cS,
                      const float* __restrict__ dmp, const float* __restrict__ dsp) {
    const float dm = *dmp, ds = *dsp;
    float km = 1.f, ks = 1.f;
#pragma unroll
    for (int i = 0; i < CHLEN; ++i) { km *= dm; ks *= ds; }
    const int gid = blockIdx.x * 256 + threadIdx.x;   // 0..32767
    const int b = gid >> 10, d = gid & 1023;
    float tM = 0.f, tS = 0.f;
    for (int c = 0; c < NCHUNK; ++c) {
        const size_t idx = (((size_t)c * BDIM + b) << 10) + d;
        float oM = cM[idx], oS = cS[idx];
        cM[idx] = tM; cS[idx] = tS;
        tM = km * tM + oM;
        tS = ks * tS + oS;
    }
}

// ---------------------------------------------------------------------------
// scan pass 3: recompute with carry-in, write out, accumulate loss; last
// block (device-scope ticket) writes the final loss scalar.
__global__ void scan3(const __bf16* __restrict__ H,
                      const f32x4* __restrict__ cM, const f32x4* __restrict__ cS,
                      const float* __restrict__ normAcc, const float* __restrict__ bias,
                      const float* __restrict__ dmp, const float* __restrict__ dsp,
                      float* __restrict__ out, float* __restrict__ lossAcc,
                      unsigned* __restrict__ ticket) {
    const float dm = *dmp, ds = *dsp;
    const int c = blockIdx.x, b = blockIdx.y, tid = threadIdx.x;
    const size_t cidx = ((size_t)c * BDIM + b) * 256 + tid;
    f32x4 M = cM[cidx];
    f32x4 S = cS[cidx];
    f32x4 nv = *(const f32x4*)(normAcc + tid * 4);
    f32x4 inv;
    inv[0] = 1.f / (nv[0] + 1e-8f); inv[1] = 1.f / (nv[1] + 1e-8f);
    inv[2] = 1.f / (nv[2] + 1e-8f); inv[3] = 1.f / (nv[3] + 1e-8f);
    f32x4 bv = *(const f32x4*)(bias + tid * 4);

    const size_t rowbase = ((size_t)b * TDIM + c * CHLEN) * OUTDIM + tid * 4;
    const __bf16* p = H + rowbase;
    float* o = out + rowbase;
    float loss = 0.f;
#pragma unroll 4
    for (int t = 0; t < CHLEN; ++t) {
        bf16x4 hv = *(const bf16x4*)(p + (size_t)t * OUTDIM);
        f32x4 h; h[0] = hv[0]; h[1] = hv[1]; h[2] = hv[2]; h[3] = hv[3];
        M = dm * (M + h);
        S = ds * (S + h);
        f32x4 r = (M - S) * inv - bv;
        *(f32x4*)(o + (size_t)t * OUTDIM) = r;
        loss += r[0] * r[0] + r[1] * r[1] + r[2] * r[2] + r[3] * r[3];
    }
    __shared__ float red[256];
    red[tid] = loss;
    __syncthreads();
    for (int s = 128; s > 0; s >>= 1) {
        if (tid < s) red[tid] += red[tid + s];
        __syncthreads();
    }
    if (tid == 0) {
        atomicAdd(lossAcc, red[0]);
        __threadfence();
        unsigned t = atomicAdd(ticket, 1u);
        if (t == NCHUNK * BDIM - 1) {
            float total = atomicAdd(lossAcc, 0.0f);   // coherent read
            out[OUT_ELEMS] = 0.5f * total / (float)OUT_ELEMS;
        }
    }
}

// ---------------------------------------------------------------------------
// Workspace layout (bytes):
//   H      (bf16 16000x1024) : 0          .. 32,768,000
//   WBT    (bf16 1024x2048)  : 32,768,000 .. 36,962,304
//   NORM   (f32 1024)        : 36,962,304 .. +4096
//   LOSS   (f32 1)           : 36,966,400
//   TICKET (u32 1)           : 36,966,404
//   CM     (f32 25*32*1024)  : 36,966,656 .. +3,276,800
//   CS                       : 40,243,456 .. +3,276,800   (end 43,520,256)
// xb (bf16 x) lives in d_out (exactly 65,536,000 B) until scan3 overwrites it.
#define OFF_H      ((size_t)0)
#define OFF_WBT    ((size_t)32768000)
#define OFF_NORM   ((size_t)36962304)
#define OFF_LOSS   ((size_t)36966400)
#define OFF_TICKET ((size_t)36966404)
#define OFF_CM     ((size_t)36966656)
#define OFF_CS     ((size_t)40243456)

extern "C" void kernel_launch(void* const* d_in, const int* in_sizes, int n_in,
                              void* d_out, int out_size, void* d_ws, size_t ws_size,
                              hipStream_t stream) {
    const float* x  = (const float*)d_in[0];
    const float* w  = (const float*)d_in[1];
    const float* bb = (const float*)d_in[2];
    const float* dm = (const float*)d_in[3];
    const float* ds = (const float*)d_in[4];

    char* ws = (char*)d_ws;
    __bf16*   H    = (__bf16*)(ws + OFF_H);
    __bf16*   WBT  = (__bf16*)(ws + OFF_WBT);
    float*    NORM = (float*)(ws + OFF_NORM);
    float*    LOSS = (float*)(ws + OFF_LOSS);
    unsigned* TICK = (unsigned*)(ws + OFF_TICKET);
    f32x4*    CM   = (f32x4*)(ws + OFF_CM);
    f32x4*    CS   = (f32x4*)(ws + OFF_CS);
    __bf16*   XB   = (__bf16*)d_out;          // scratch: bf16 x (exact fit)
    float*    out  = (float*)d_out;

    hipMemsetAsync(ws + OFF_NORM, 0, 4096 + 256, stream);   // NORM+LOSS+TICKET

    convert_x<<<16000, 256, 0, stream>>>(x, XB);
    transpose_w<<<dim3(32, 64), dim3(32, 8), 0, stream>>>(w, WBT, NORM);
    gemm_bf16<<<dim3(4, 125), 256, 0, stream>>>(XB, WBT, H);
    scan1<<<dim3(NCHUNK, BDIM), 256, 0, stream>>>(H, CM, CS, dm, ds);
    scan2<<<128, 256, 0, stream>>>((float*)CM, (float*)CS, dm, ds);
    scan3<<<dim3(NCHUNK, BDIM), 256, 0, stream>>>(H, CM, CS, NORM, bb, dm, ds,
                                                  out, LOSS, TICK);
}